// Round 1
// baseline (20227.280 us; speedup 1.0000x reference)
//
#include <hip/hip_runtime.h>
#include <math.h>

#define BB 64      // batch
#define TT 512     // encoder time
#define NS 128     // decode steps
#define SD 512     // lstm hidden
#define ATT 128
#define NC 64      // num classes
#define IND 576    // NC + 512

__device__ __forceinline__ float sigm(float x) { return 1.0f / (1.0f + expf(-x)); }

// ---------------- init: zero states (slot 0) + ctx = h[:,0,:] ----------------
__global__ void init_kernel(const float* __restrict__ h,
                            float* __restrict__ h1, float* __restrict__ c1,
                            float* __restrict__ h2, float* __restrict__ c2,
                            float* __restrict__ ctx)
{
    int idx = blockIdx.x * 512 + threadIdx.x;   // 64 blocks * 512 = 32768
    h1[idx] = 0.f; c1[idx] = 0.f; h2[idx] = 0.f; c2[idx] = 0.f;
    int b = idx >> 9, d = idx & 511;
    ctx[idx] = h[(size_t)b * TT * SD + d];
}

// ---------------- fused LSTM cell: gates GEMM + elementwise ----------------
// g[b,j] = b1[j]+b2[j] + (onehot? Woh[j, x[b,t]]) + X1[b,:]·W1[j,off1:off1+512] + X2[b,:]·W2[j,:512]
// j = q*512 + d, q in {i,f,g,o}
__global__ __launch_bounds__(256) void lstm_kernel(
    const float* __restrict__ X1, const float* __restrict__ X2,
    const float* __restrict__ W1, int ldw1, int off1,
    const float* __restrict__ W2,
    const float* __restrict__ b1, const float* __restrict__ b2,
    const int* __restrict__ xtok, int t, const float* __restrict__ Woh,
    const float* __restrict__ c_in, float* __restrict__ c_out,
    float* __restrict__ h_out, float* __restrict__ sc_out)
{
    __shared__ __align__(16) float Xs[8 * 1024];
    __shared__ float Ls[8][8][4];
    int tid = threadIdx.x;
    int b0 = (blockIdx.x >> 6) << 3;   // 8 b-tiles
    int d0 = (blockIdx.x & 63) << 3;   // 64 d-tiles of 8

    for (int i = tid; i < 1024; i += 256) {
        int rb = i >> 7, kq = i & 127;
        *(float4*)(Xs + rb * 1024 + kq * 4)       = *(const float4*)(X1 + (b0 + rb) * SD + kq * 4);
        *(float4*)(Xs + rb * 1024 + 512 + kq * 4) = *(const float4*)(X2 + (b0 + rb) * SD + kq * 4);
    }
    __syncthreads();

    int bb = tid >> 5, dd = (tid >> 2) & 7, q = tid & 3;
    int b = b0 + bb, d = d0 + dd, j = q * SD + d;
    float acc = b1[j] + b2[j];
    if (Woh) acc += Woh[(size_t)j * ldw1 + xtok[b * NS + t]];
    const float* w1 = W1 + (size_t)j * ldw1 + off1;
    const float* w2 = W2 + (size_t)j * SD;
    const float* xs = Xs + bb * 1024;
#pragma unroll 8
    for (int k = 0; k < SD; k += 4) {
        float4 xv = *(const float4*)(xs + k);
        float4 wv = *(const float4*)(w1 + k);
        acc += xv.x * wv.x + xv.y * wv.y + xv.z * wv.z + xv.w * wv.w;
    }
#pragma unroll 8
    for (int k = 0; k < SD; k += 4) {
        float4 xv = *(const float4*)(xs + 512 + k);
        float4 wv = *(const float4*)(w2 + k);
        acc += xv.x * wv.x + xv.y * wv.y + xv.z * wv.z + xv.w * wv.w;
    }
    Ls[bb][dd][q] = acc;
    __syncthreads();
    if (q == 0) {
        float gi = Ls[bb][dd][0];
        float gf = Ls[bb][dd][1];
        float gg = Ls[bb][dd][2];
        float go = Ls[bb][dd][3];
        float ci = c_in[b * SD + d];
        float cn = sigm(gf) * ci + sigm(gi) * tanhf(gg);
        float hn = sigm(go) * tanhf(cn);
        c_out[b * SD + d] = cn;
        h_out[b * SD + d] = hn;
        if (sc_out) sc_out[((size_t)b * NS + t) * 1024 + d] = hn;
    }
}

// ---------------- attention part 1: phi = h2·Wphi^T+bphi, e = phi·psi, softmax ----------------
__global__ __launch_bounds__(256) void attn1_kernel(
    const float* __restrict__ h2,
    const float* __restrict__ Wphi, const float* __restrict__ bphi,
    const float* __restrict__ psi,
    float* __restrict__ alpha)
{
    int b = blockIdx.x, tid = threadIdx.x;
    __shared__ __align__(16) float h2s[512];
    __shared__ __align__(16) float phis[128];
    __shared__ float es[512];
    __shared__ float red[256];

    h2s[tid] = h2[b * SD + tid];
    h2s[256 + tid] = h2[b * SD + 256 + tid];
    __syncthreads();

    if (tid < 128) {
        float acc = bphi[tid];
        const float* w = Wphi + (size_t)tid * SD;
#pragma unroll 8
        for (int k = 0; k < SD; k += 4) {
            float4 xv = *(const float4*)(h2s + k);
            float4 wv = *(const float4*)(w + k);
            acc += xv.x * wv.x + xv.y * wv.y + xv.z * wv.z + xv.w * wv.w;
        }
        phis[tid] = acc;
    }
    __syncthreads();

    for (int tt = 0; tt < 2; ++tt) {
        int t = tid + tt * 256;
        const float* pr = psi + ((size_t)b * TT + t) * ATT;
        float acc = 0.f;
#pragma unroll 8
        for (int k = 0; k < ATT; k += 4) {
            float4 xv = *(const float4*)(pr + k);
            float4 wv = *(const float4*)(phis + k);
            acc += xv.x * wv.x + xv.y * wv.y + xv.z * wv.z + xv.w * wv.w;
        }
        es[t] = acc;
    }
    __syncthreads();

    red[tid] = fmaxf(es[tid], es[tid + 256]);
    __syncthreads();
    for (int st = 128; st > 0; st >>= 1) {
        if (tid < st) red[tid] = fmaxf(red[tid], red[tid + st]);
        __syncthreads();
    }
    float mx = red[0];
    __syncthreads();
    float e0 = expf(es[tid] - mx);
    float e1 = expf(es[tid + 256] - mx);
    es[tid] = e0; es[tid + 256] = e1;
    red[tid] = e0 + e1;
    __syncthreads();
    for (int st = 128; st > 0; st >>= 1) {
        if (tid < st) red[tid] += red[tid + st];
        __syncthreads();
    }
    float inv = 1.0f / red[0];
    alpha[b * TT + tid] = es[tid] * inv;
    alpha[b * TT + 256 + tid] = es[256 + tid] * inv;
}

// ---------------- attention part 2: ctx = alpha · h ----------------
__global__ __launch_bounds__(256) void attn2_kernel(
    const float* __restrict__ alpha, const float* __restrict__ h,
    float* __restrict__ ctx, float* __restrict__ sc_out, int t)
{
    // grid 256 = 64 b * 4 d-chunks(128); block 256 = 128 d * 2 t-halves
    int b = blockIdx.x >> 2;
    int d0 = (blockIdx.x & 3) << 7;
    int tid = threadIdx.x;
    int d = d0 + (tid & 127);
    int th = tid >> 7;
    const float* al = alpha + b * TT + th * 256;
    const float* hp = h + ((size_t)b * TT + th * 256) * SD + d;
    float acc = 0.f;
#pragma unroll 8
    for (int k = 0; k < 256; ++k) acc += al[k] * hp[(size_t)k * SD];
    __shared__ float part[256];
    part[tid] = acc;
    __syncthreads();
    if (th == 0) {
        float v = acc + part[tid + 128];
        ctx[b * SD + d] = v;
        sc_out[((size_t)b * NS + t) * 1024 + 512 + d] = v;
    }
}

// ---------------- generic tiled GEMM: C[m,n] = A[m,:K]·W[n,:K] + bias[n] ----------------
// tile 64x64, TK=32, k-major LDS tiles, thread = 4x4 outer product
__global__ __launch_bounds__(256) void gemm_bias_kernel(
    const float* __restrict__ A, int lda,
    const float* __restrict__ W, int ldw,
    const float* __restrict__ bias,
    float* __restrict__ C, int ldc, int K)
{
    __shared__ __align__(16) float As[32][64];
    __shared__ __align__(16) float Ws[32][64];
    int tid = threadIdx.x;
    int m0 = blockIdx.x * 64, n0 = blockIdx.y * 64;
    int tm = tid >> 4, tn = tid & 15;
    float acc[4][4] = {};

    for (int k0 = 0; k0 < K; k0 += 32) {
#pragma unroll
        for (int i = 0; i < 2; ++i) {
            int fidx = tid + i * 256;       // 0..511
            int r = fidx & 63, fc = fidx >> 6;  // fc 0..7
            float4 av = *(const float4*)(A + (size_t)(m0 + r) * lda + k0 + fc * 4);
            As[fc * 4 + 0][r] = av.x; As[fc * 4 + 1][r] = av.y;
            As[fc * 4 + 2][r] = av.z; As[fc * 4 + 3][r] = av.w;
            float4 wv = *(const float4*)(W + (size_t)(n0 + r) * ldw + k0 + fc * 4);
            Ws[fc * 4 + 0][r] = wv.x; Ws[fc * 4 + 1][r] = wv.y;
            Ws[fc * 4 + 2][r] = wv.z; Ws[fc * 4 + 3][r] = wv.w;
        }
        __syncthreads();
#pragma unroll 8
        for (int k = 0; k < 32; ++k) {
            float4 a4 = *(const float4*)(&As[k][tm * 4]);
            float4 b4 = *(const float4*)(&Ws[k][tn * 4]);
            acc[0][0] += a4.x * b4.x; acc[0][1] += a4.x * b4.y; acc[0][2] += a4.x * b4.z; acc[0][3] += a4.x * b4.w;
            acc[1][0] += a4.y * b4.x; acc[1][1] += a4.y * b4.y; acc[1][2] += a4.y * b4.z; acc[1][3] += a4.y * b4.w;
            acc[2][0] += a4.z * b4.x; acc[2][1] += a4.z * b4.y; acc[2][2] += a4.z * b4.z; acc[2][3] += a4.z * b4.w;
            acc[3][0] += a4.w * b4.x; acc[3][1] += a4.w * b4.y; acc[3][2] += a4.w * b4.z; acc[3][3] += a4.w * b4.w;
        }
        __syncthreads();
    }
    float4 b4 = *(const float4*)(bias + n0 + tn * 4);
#pragma unroll
    for (int r = 0; r < 4; ++r) {
        int m = m0 + tm * 4 + r;
        float4 o;
        o.x = acc[r][0] + b4.x; o.y = acc[r][1] + b4.y;
        o.z = acc[r][2] + b4.z; o.w = acc[r][3] + b4.w;
        *(float4*)(C + (size_t)m * ldc + n0 + tn * 4) = o;
    }
}

extern "C" void kernel_launch(void* const* d_in, const int* in_sizes, int n_in,
                              void* d_out, int out_size, void* d_ws, size_t ws_size,
                              hipStream_t stream)
{
    const int*   x    = (const int*)  d_in[0];
    const float* h    = (const float*)d_in[1];
    const float* Wih0 = (const float*)d_in[2];
    const float* Whh0 = (const float*)d_in[3];
    const float* bih0 = (const float*)d_in[4];
    const float* bhh0 = (const float*)d_in[5];
    const float* Wih1 = (const float*)d_in[6];
    const float* Whh1 = (const float*)d_in[7];
    const float* bih1 = (const float*)d_in[8];
    const float* bhh1 = (const float*)d_in[9];
    const float* Wphi = (const float*)d_in[10];
    const float* bphi = (const float*)d_in[11];
    const float* Wpsi = (const float*)d_in[12];
    const float* bpsi = (const float*)d_in[13];
    const float* Wcd  = (const float*)d_in[14];
    const float* bcd  = (const float*)d_in[15];
    float* out = (float*)d_out;

    float* ws = (float*)d_ws;
    float* psi   = ws;  ws += (size_t)BB * TT * ATT;      // 4,194,304
    float* alpha = ws;  ws += BB * TT;                    // 32,768
    float* h1b   = ws;  ws += 2 * BB * SD;
    float* c1b   = ws;  ws += 2 * BB * SD;
    float* h2b   = ws;  ws += 2 * BB * SD;
    float* c2b   = ws;  ws += 2 * BB * SD;
    float* ctx   = ws;  ws += BB * SD;
    float* sc    = ws;  ws += (size_t)BB * NS * 1024;     // 8,388,608  (total ~51.6 MB)

    init_kernel<<<64, 512, 0, stream>>>(h, h1b, c1b, h2b, c2b, ctx);
    // psi_h = h @ Wpsi^T + bpsi : M=32768, N=128, K=512
    gemm_bias_kernel<<<dim3(512, 2), 256, 0, stream>>>(h, SD, Wpsi, SD, bpsi, psi, ATT, SD);

    int s = 0;
    for (int t = 0; t < NS; ++t) {
        float* h1i = h1b + s * BB * SD; float* h1o = h1b + (s ^ 1) * BB * SD;
        float* c1i = c1b + s * BB * SD; float* c1o = c1b + (s ^ 1) * BB * SD;
        float* h2i = h2b + s * BB * SD; float* h2o = h2b + (s ^ 1) * BB * SD;
        float* c2i = c2b + s * BB * SD; float* c2o = c2b + (s ^ 1) * BB * SD;
        // LSTM layer 0: inp = [onehot(x[:,t]), ctx], recurrent h1
        lstm_kernel<<<512, 256, 0, stream>>>(ctx, h1i, Wih0, IND, NC, Whh0, bih0, bhh0,
                                             x, t, Wih0, c1i, c1o, h1o, nullptr);
        // LSTM layer 1: inp = h1_new, recurrent h2; also store s into sc[:, :512]
        lstm_kernel<<<512, 256, 0, stream>>>(h1o, h2i, Wih1, SD, 0, Whh1, bih1, bhh1,
                                             nullptr, t, nullptr, c2i, c2o, h2o, sc);
        attn1_kernel<<<64, 256, 0, stream>>>(h2o, Wphi, bphi, psi, alpha);
        attn2_kernel<<<256, 256, 0, stream>>>(alpha, h, ctx, sc, t);
        s ^= 1;
    }
    // p = [s, ctx] @ Wcd^T + bcd : M=8192, N=64, K=1024  -> out (B,N,64)
    gemm_bias_kernel<<<dim3(128, 1), 256, 0, stream>>>(sc, 1024, Wcd, 1024, bcd, out, NC, 1024);
}

// Round 2
// 5686.354 us; speedup vs baseline: 3.5572x; 3.5572x over previous
//
#include <hip/hip_runtime.h>
#include <hip/hip_bf16.h>
#include <math.h>

#define BB 64      // batch
#define TT 512     // encoder time
#define NS 128     // decode steps
#define SD 512     // lstm hidden
#define ATT 128
#define NC 64      // num classes
#define KA 1152    // augmented K: 512 ctx/in + 512 rec + 64 onehot + 1 bias + 63 pad

typedef __attribute__((ext_vector_type(8))) short bf8;   // 8 bf16 (4 VGPRs)
typedef __attribute__((ext_vector_type(4))) float f4;

__device__ __forceinline__ float sigm(float x) { return 1.0f / (1.0f + expf(-x)); }
__device__ __forceinline__ float b2f(short s) {
    union { unsigned u; float f; } c; c.u = ((unsigned)(unsigned short)s) << 16; return c.f;
}
#define MFMA16(a, b, c) __builtin_amdgcn_mfma_f32_16x16x32_bf16((a), (b), (c), 0, 0, 0)

// ---------------- fp32 -> bf16 convert (vec4) ----------------
__global__ void f2b_kernel(const float* __restrict__ src, __hip_bfloat16* __restrict__ dst, int n)
{
    int i = (blockIdx.x * blockDim.x + threadIdx.x) * 4;
    if (i < n) {
        float4 v = *(const float4*)(src + i);
        dst[i]     = __hip_bfloat16(v.x);
        dst[i + 1] = __hip_bfloat16(v.y);
        dst[i + 2] = __hip_bfloat16(v.z);
        dst[i + 3] = __hip_bfloat16(v.w);
    }
}

// ---------------- build augmented LSTM0 weights, gate-interleaved ----------------
// W1[np][kk], np = 4*d+q -> j = q*512+d
__global__ void prep_w1_kernel(const float* __restrict__ Wih, const float* __restrict__ Whh,
                               const float* __restrict__ bih, const float* __restrict__ bhh,
                               __hip_bfloat16* __restrict__ W)
{
    int idx = blockIdx.x * blockDim.x + threadIdx.x;   // 2048*1152
    if (idx >= 2048 * KA) return;
    int np = idx / KA, kk = idx - np * KA;
    int q = np & 3, d = np >> 2, j = q * 512 + d;
    float v = 0.f;
    if (kk < 512)        v = Wih[j * 576 + 64 + kk];        // ctx part of Wih0
    else if (kk < 1024)  v = Whh[j * 512 + kk - 512];       // Whh0
    else if (kk < 1088)  v = Wih[j * 576 + kk - 1024];      // onehot part
    else if (kk == 1088) v = bih[j] + bhh[j];               // bias via ones column
    W[idx] = __hip_bfloat16(v);
}

// ---------------- build augmented LSTM1 weights ----------------
__global__ void prep_w2_kernel(const float* __restrict__ Wih, const float* __restrict__ Whh,
                               const float* __restrict__ bih, const float* __restrict__ bhh,
                               __hip_bfloat16* __restrict__ W)
{
    int idx = blockIdx.x * blockDim.x + threadIdx.x;
    if (idx >= 2048 * KA) return;
    int np = idx / KA, kk = idx - np * KA;
    int q = np & 3, d = np >> 2, j = q * 512 + d;
    float v = 0.f;
    if (kk < 512)        v = Wih[j * 512 + kk];
    else if (kk < 1024)  v = Whh[j * 512 + kk - 512];
    else if (kk == 1088) v = bih[j] + bhh[j];
    W[idx] = __hip_bfloat16(v);
}

// ---------------- init: X buffers, c states ----------------
__global__ void init_kernel(const float* __restrict__ h, const int* __restrict__ x,
                            __hip_bfloat16* __restrict__ X1a, __hip_bfloat16* __restrict__ X1b,
                            __hip_bfloat16* __restrict__ X2a, __hip_bfloat16* __restrict__ X2b,
                            float* __restrict__ c1, float* __restrict__ c2)
{
    int idx = blockIdx.x * blockDim.x + threadIdx.x;   // 64*1152
    if (idx >= 64 * KA) return;
    int b = idx / KA, col = idx - b * KA;
    __hip_bfloat16 zero(0.0f), one(1.0f);
    __hip_bfloat16 v1a = zero, vo = zero;
    if (col < 512)        v1a = __hip_bfloat16(h[(size_t)b * TT * SD + col]);  // ctx0 = h[:,0,:]
    else if (col >= 1024 && col < 1088) v1a = (x[b * NS] == col - 1024) ? one : zero;
    if (col == 1088) { v1a = one; vo = one; }
    X1a[idx] = v1a; X1b[idx] = vo; X2a[idx] = vo; X2b[idx] = vo;
    if (idx < 512 * 64) { c1[idx] = 0.f; c2[idx] = 0.f; }
}

// ---------------- fused LSTM gates GEMM (MFMA) + cell ----------------
// C[np][b] = sum_k W[np][k] * X[b][k]; np = 4d+q interleave -> one thread holds
// (i,f,g,o) for a single d in its 4 accum regs. Grid 128 blocks x 64 threads.
__global__ __launch_bounds__(64) void lstm_step_kernel(
    const __hip_bfloat16* __restrict__ X,    // [64][1152]
    const __hip_bfloat16* __restrict__ W,    // [2048][1152]
    float* __restrict__ c,                   // [512][64] in-place
    __hip_bfloat16* __restrict__ dst1, int rs1,   // h out: dst[b*rs + d]
    __hip_bfloat16* __restrict__ dst2, int rs2)
{
    int lane = threadIdx.x;
    int m0 = blockIdx.x * 16;
    int mr = lane & 15, quad = lane >> 4;
    const bf8* Ar = (const bf8*)(W + (size_t)(m0 + mr) * KA + quad * 8);
    const bf8* B0 = (const bf8*)(X + (size_t)(mr)      * KA + quad * 8);
    const bf8* B1 = (const bf8*)(X + (size_t)(16 + mr) * KA + quad * 8);
    const bf8* B2 = (const bf8*)(X + (size_t)(32 + mr) * KA + quad * 8);
    const bf8* B3 = (const bf8*)(X + (size_t)(48 + mr) * KA + quad * 8);
    f4 acc0 = {0,0,0,0}, acc1 = {0,0,0,0}, acc2 = {0,0,0,0}, acc3 = {0,0,0,0};
#pragma unroll 6
    for (int k0 = 0; k0 < KA; k0 += 32) {
        int ko = k0 >> 3;               // bf8 index; lane's k = k0 + quad*8
        bf8 a  = Ar[ko];
        bf8 b0 = B0[ko], b1 = B1[ko], b2 = B2[ko], b3 = B3[ko];
        acc0 = MFMA16(a, b0, acc0);
        acc1 = MFMA16(a, b1, acc1);
        acc2 = MFMA16(a, b2, acc2);
        acc3 = MFMA16(a, b3, acc3);
    }
    // C layout: col = lane&15 (batch within nfrag), row = quad*4+reg (np local)
    int d = (m0 >> 2) + quad;           // rows quad*4+{0..3} = one d, q = reg
    f4 accs[4] = {acc0, acc1, acc2, acc3};
#pragma unroll
    for (int nf = 0; nf < 4; ++nf) {
        int b = nf * 16 + mr;
        f4 g = accs[nf];                // x=i, y=f, z=g, w=o
        int ci = d * 64 + b;
        float cn = sigm(g.y) * c[ci] + sigm(g.x) * tanhf(g.z);
        float hn = sigm(g.w) * tanhf(cn);
        c[ci] = cn;
        __hip_bfloat16 hb(hn);
        dst1[(size_t)b * rs1 + d] = hb;
        dst2[(size_t)b * rs2 + d] = hb;
    }
}

// ---------------- psi GEMM: psibf[b*512+t][128] = hbf @ Wpsi^T + bpsi ----------------
__global__ __launch_bounds__(256) void psi_gemm_kernel(
    const __hip_bfloat16* __restrict__ A,   // hbf [32768][512]
    const __hip_bfloat16* __restrict__ Bw,  // Wpsibf [128][512]
    const float* __restrict__ bias,
    __hip_bfloat16* __restrict__ C)         // [32768][128]
{
    int lane = threadIdx.x & 63, wave = threadIdx.x >> 6;
    int m0 = (blockIdx.x * 4 + wave) * 16;
    int mr = lane & 15, quad = lane >> 4;
    const bf8* Ar = (const bf8*)(A + (size_t)(m0 + mr) * 512 + quad * 8);
    f4 acc[8] = {};
    for (int k0 = 0; k0 < 512; k0 += 32) {
        int ko = k0 >> 3;
        bf8 a = Ar[ko];
#pragma unroll
        for (int nf = 0; nf < 8; ++nf) {
            const bf8* Br = (const bf8*)(Bw + (size_t)(nf * 16 + mr) * 512 + quad * 8);
            acc[nf] = MFMA16(a, Br[ko], acc[nf]);
        }
    }
#pragma unroll
    for (int nf = 0; nf < 8; ++nf) {
        int n = nf * 16 + mr;
        float bs = bias[n];
#pragma unroll
        for (int r = 0; r < 4; ++r) {
            int m = m0 + quad * 4 + r;
            C[(size_t)m * 128 + n] = __hip_bfloat16(acc[nf][r] + bs);
        }
    }
}

// ---------------- final projection: out[b*128+t][64] = scbf @ Wcd^T + bcd ----------------
__global__ __launch_bounds__(256) void out_gemm_kernel(
    const __hip_bfloat16* __restrict__ A,   // scbf [8192][1024]
    const __hip_bfloat16* __restrict__ Bw,  // Wcdbf [64][1024]
    const float* __restrict__ bias,
    float* __restrict__ C)                  // [8192][64]
{
    int lane = threadIdx.x & 63, wave = threadIdx.x >> 6;
    int m0 = (blockIdx.x * 4 + wave) * 16;
    int mr = lane & 15, quad = lane >> 4;
    const bf8* Ar = (const bf8*)(A + (size_t)(m0 + mr) * 1024 + quad * 8);
    f4 acc[4] = {};
    for (int k0 = 0; k0 < 1024; k0 += 32) {
        int ko = k0 >> 3;
        bf8 a = Ar[ko];
#pragma unroll
        for (int nf = 0; nf < 4; ++nf) {
            const bf8* Br = (const bf8*)(Bw + (size_t)(nf * 16 + mr) * 1024 + quad * 8);
            acc[nf] = MFMA16(a, Br[ko], acc[nf]);
        }
    }
#pragma unroll
    for (int nf = 0; nf < 4; ++nf) {
        int n = nf * 16 + mr;
        float bs = bias[n];
#pragma unroll
        for (int r = 0; r < 4; ++r) {
            int m = m0 + quad * 4 + r;
            C[(size_t)m * 64 + n] = acc[nf][r] + bs;
        }
    }
}

// ---------------- fused attention step ----------------
// grid 256 = 64 b x 4 d-chunks; softmax computed redundantly per d-chunk.
__global__ __launch_bounds__(256) void attn_step_kernel(
    const __hip_bfloat16* __restrict__ X2n,  // h2 at cols 512:1024
    const __hip_bfloat16* __restrict__ Wphib, const float* __restrict__ bphi,
    const __hip_bfloat16* __restrict__ psib,  // [b*512+t][128]
    const __hip_bfloat16* __restrict__ hbf,   // [b][512][512]
    __hip_bfloat16* __restrict__ X1n,         // ctx -> cols 0:512, OH -> 1024:1088
    __hip_bfloat16* __restrict__ scb,         // + (b*128+t)*1024 + 512 + d
    const int* __restrict__ xtok, int t)
{
    int b = blockIdx.x >> 2, dch = blockIdx.x & 3;
    int tid = threadIdx.x;
    __shared__ float h2s[512];
    __shared__ float phis[128];
    __shared__ float es[512];
    __shared__ float red[256];

    h2s[tid]       = b2f(((const short*)X2n)[b * KA + 512 + tid]);
    h2s[256 + tid] = b2f(((const short*)X2n)[b * KA + 768 + tid]);
    __syncthreads();

    // phi[a] = h2 . Wphi[a] + bphi[a];  4 lanes/row, 64B-line merged loads
    {
        int al = tid & 3;
#pragma unroll
        for (int pass = 0; pass < 2; ++pass) {
            int a = pass * 64 + (tid >> 2);
            const bf8* wr = (const bf8*)(Wphib + (size_t)a * 512 + al * 8);
            float acc = 0.f;
#pragma unroll
            for (int i = 0; i < 16; ++i) {
                bf8 wv = wr[i * 4];                 // elems (i*4+al)*8 ..
                const float* hp = h2s + i * 32 + al * 8;
#pragma unroll
                for (int j = 0; j < 8; ++j) acc += hp[j] * b2f(wv[j]);
            }
            acc += __shfl_xor(acc, 1);
            acc += __shfl_xor(acc, 2);
            if (al == 0) phis[a] = acc + bphi[a];
        }
    }
    __syncthreads();

    // e[t'] = phi . psi[b][t'];  4 lanes/row
    {
        int al = tid & 3;
#pragma unroll
        for (int pass = 0; pass < 8; ++pass) {
            int tt = pass * 64 + (tid >> 2);
            const bf8* pr = (const bf8*)(psib + (size_t)(b * TT + tt) * 128 + al * 8);
            float acc = 0.f;
#pragma unroll
            for (int i = 0; i < 4; ++i) {
                bf8 pv = pr[i * 4];
                const float* ph = phis + i * 32 + al * 8;
#pragma unroll
                for (int j = 0; j < 8; ++j) acc += ph[j] * b2f(pv[j]);
            }
            acc += __shfl_xor(acc, 1);
            acc += __shfl_xor(acc, 2);
            if (al == 0) es[tt] = acc;
        }
    }
    __syncthreads();

    // softmax (unnormalized; fold 1/sum into ctx)
    red[tid] = fmaxf(es[tid], es[tid + 256]);
    __syncthreads();
    for (int st = 128; st > 0; st >>= 1) {
        if (tid < st) red[tid] = fmaxf(red[tid], red[tid + st]);
        __syncthreads();
    }
    float mx = red[0];
    __syncthreads();
    float e0 = expf(es[tid] - mx), e1 = expf(es[tid + 256] - mx);
    es[tid] = e0; es[tid + 256] = e1;
    red[tid] = e0 + e1;
    __syncthreads();
    for (int st = 128; st > 0; st >>= 1) {
        if (tid < st) red[tid] += red[tid + st];
        __syncthreads();
    }
    float inv = 1.0f / red[0];
    __syncthreads();

    // ctx[d] = inv * sum_t es[t] * h[b][t][d], d-chunk of 128
    {
        int d = dch * 128 + (tid & 127), th = tid >> 7;
        const short* hp = (const short*)hbf + ((size_t)b * TT + th * 256) * SD + d;
        float a0 = 0.f, a1 = 0.f, a2 = 0.f, a3 = 0.f;
#pragma unroll 4
        for (int k = 0; k < 256; k += 4) {
            a0 += es[th * 256 + k]     * b2f(hp[(size_t)k * SD]);
            a1 += es[th * 256 + k + 1] * b2f(hp[(size_t)(k + 1) * SD]);
            a2 += es[th * 256 + k + 2] * b2f(hp[(size_t)(k + 2) * SD]);
            a3 += es[th * 256 + k + 3] * b2f(hp[(size_t)(k + 3) * SD]);
        }
        float acc = (a0 + a1) + (a2 + a3);
        red[tid] = acc;
        __syncthreads();
        if (th == 0) {
            float v = (acc + red[tid + 128]) * inv;
            __hip_bfloat16 vb(v);
            X1n[b * KA + d] = vb;
            scb[((size_t)b * NS + t) * 1024 + 512 + d] = vb;
        }
    }
    // onehot for step t+1 (redundant identical writes across d-chunks are benign)
    if (tid < 64) {
        float v = (t + 1 < NS && xtok[b * NS + t + 1] == tid) ? 1.0f : 0.0f;
        X1n[b * KA + 1024 + tid] = __hip_bfloat16(v);
    }
}

extern "C" void kernel_launch(void* const* d_in, const int* in_sizes, int n_in,
                              void* d_out, int out_size, void* d_ws, size_t ws_size,
                              hipStream_t stream)
{
    const int*   x    = (const int*)  d_in[0];
    const float* h    = (const float*)d_in[1];
    const float* Wih0 = (const float*)d_in[2];
    const float* Whh0 = (const float*)d_in[3];
    const float* bih0 = (const float*)d_in[4];
    const float* bhh0 = (const float*)d_in[5];
    const float* Wih1 = (const float*)d_in[6];
    const float* Whh1 = (const float*)d_in[7];
    const float* bih1 = (const float*)d_in[8];
    const float* bhh1 = (const float*)d_in[9];
    const float* Wphi = (const float*)d_in[10];
    const float* bphi = (const float*)d_in[11];
    const float* Wpsi = (const float*)d_in[12];
    const float* bpsi = (const float*)d_in[13];
    const float* Wcd  = (const float*)d_in[14];
    const float* bcd  = (const float*)d_in[15];
    float* out = (float*)d_out;

    char* p = (char*)d_ws;
    __hip_bfloat16* hbf    = (__hip_bfloat16*)p; p += (size_t)BB * TT * SD * 2;   // 32 MB
    __hip_bfloat16* psibf  = (__hip_bfloat16*)p; p += (size_t)BB * TT * ATT * 2;  // 8 MB
    __hip_bfloat16* scbf   = (__hip_bfloat16*)p; p += (size_t)BB * NS * 1024 * 2; // 16 MB
    __hip_bfloat16* W1aug  = (__hip_bfloat16*)p; p += (size_t)2048 * KA * 2;      // 4.5 MB
    __hip_bfloat16* W2aug  = (__hip_bfloat16*)p; p += (size_t)2048 * KA * 2;      // 4.5 MB
    __hip_bfloat16* Wphib  = (__hip_bfloat16*)p; p += (size_t)ATT * SD * 2;
    __hip_bfloat16* Wpsib  = (__hip_bfloat16*)p; p += (size_t)ATT * SD * 2;
    __hip_bfloat16* Wcdb   = (__hip_bfloat16*)p; p += (size_t)NC * 1024 * 2;
    __hip_bfloat16* X1[2]; X1[0] = (__hip_bfloat16*)p; p += (size_t)BB * KA * 2;
    X1[1] = (__hip_bfloat16*)p; p += (size_t)BB * KA * 2;
    __hip_bfloat16* X2[2]; X2[0] = (__hip_bfloat16*)p; p += (size_t)BB * KA * 2;
    X2[1] = (__hip_bfloat16*)p; p += (size_t)BB * KA * 2;
    float* c1 = (float*)p; p += (size_t)SD * BB * 4;
    float* c2 = (float*)p; p += (size_t)SD * BB * 4;

    // ---- one-time prep ----
    f2b_kernel<<<16384, 256, 0, stream>>>(h, hbf, BB * TT * SD);
    f2b_kernel<<<64, 256, 0, stream>>>(Wphi, Wphib, ATT * SD);
    f2b_kernel<<<64, 256, 0, stream>>>(Wpsi, Wpsib, ATT * SD);
    f2b_kernel<<<64, 256, 0, stream>>>(Wcd, Wcdb, NC * 1024);
    prep_w1_kernel<<<(2048 * KA + 255) / 256, 256, 0, stream>>>(Wih0, Whh0, bih0, bhh0, W1aug);
    prep_w2_kernel<<<(2048 * KA + 255) / 256, 256, 0, stream>>>(Wih1, Whh1, bih1, bhh1, W2aug);
    init_kernel<<<(64 * KA + 255) / 256, 256, 0, stream>>>(h, x, X1[0], X1[1], X2[0], X2[1], c1, c2);
    psi_gemm_kernel<<<512, 256, 0, stream>>>(hbf, Wpsib, bpsi, psibf);

    // ---- decode loop: 3 kernels per step ----
    for (int t = 0; t < NS; ++t) {
        __hip_bfloat16* X1c = X1[t & 1], *X1n = X1[(t + 1) & 1];
        __hip_bfloat16* X2c = X2[t & 1], *X2n = X2[(t + 1) & 1];
        // LSTM0: reads [ctx|h1|oh|1], h1 -> X2c[:,0:512] (for LSTM1 now) + X1n[:,512:1024] (recurrent)
        lstm_step_kernel<<<128, 64, 0, stream>>>(X1c, W1aug, c1,
                                                 X2c, KA, X1n + 512, KA);
        // LSTM1: reads [h1|h2|0|1], h2 -> X2n[:,512:1024] (recurrent + attn) + scbf[:,t,0:512]
        lstm_step_kernel<<<128, 64, 0, stream>>>(X2c, W2aug, c2,
                                                 X2n + 512, KA, scbf + (size_t)t * 1024, NS * 1024);
        // attention: ctx -> X1n[:,0:512] + scbf[:,t,512:1024]; onehot(t+1) -> X1n[:,1024:1088]
        attn_step_kernel<<<256, 256, 0, stream>>>(X2n, Wphib, bphi, psibf, hbf,
                                                  X1n, scbf, x, t);
    }
    // output projection
    out_gemm_kernel<<<128, 256, 0, stream>>>(scbf, Wcdb, bcd, out);
}